// Round 1
// 1195.284 us; speedup vs baseline: 1.3583x; 1.3583x over previous
//
#include <hip/hip_runtime.h>
#include <hip/hip_bf16.h>

// Problem: L=4, N=256 queries, M=51200 gallery, D=1024.
// out[n] = 1 - mean_l max_m cos(q[l,n], g[l,m]), eps=1e-8 on norms.
// Roofline: G stream = 800 MB -> ~130 us floor. Previous version was
// latency-bound (MfmaUtil 5.6%, HBM 8.9%): per-lane HBM loads, 4x redundant
// across waves, drained every K-step. This version: m97-style LDS pipeline.
//   - G tile (64 rows x 32 dims fp32, 8KB) staged via global_load_lds w=16,
//     double-buffered, shared by all 4 waves (4x fewer global loads).
//   - XOR bank-swizzle (byte ^= (row&7)<<4), applied on the PRE-SWIZZLED
//     GLOBAL SOURCE address (linear LDS dest, rule: both-sides-or-neither)
//     and on the ds_read_b128 addresses -> conflict-free.
//   - Q pre-converted to bf16 in the norm prepass; A-frags are 16B global
//     loads (L2-hot, 2MB), prefetched one K-step ahead in registers.
//   - fp32->bf16 cvt + gallery sumsq for G stay in-loop (identical numerics
//     to previous version: same values, same accumulation order).

#define L_LAYERS 4
#define N_Q 256
#define M_G 51200
#define K_D 1024
#define BM 64
#define NCHUNK (M_G / BM)   // 800
#define KSTEPS (K_D / 32)   // 32

typedef __bf16 bf16x8 __attribute__((ext_vector_type(8)));
typedef float  f32x4  __attribute__((ext_vector_type(4)));

__device__ __forceinline__ bf16x8 cvt8(f32x4 a, f32x4 b) {
    bf16x8 r;
    r[0] = (__bf16)a[0]; r[1] = (__bf16)a[1]; r[2] = (__bf16)a[2]; r[3] = (__bf16)a[3];
    r[4] = (__bf16)b[0]; r[5] = (__bf16)b[1]; r[6] = (__bf16)b[2]; r[7] = (__bf16)b[3];
    return r;
}

__device__ __forceinline__ void gload16(const void* g, void* lds) {
    __builtin_amdgcn_global_load_lds((const __attribute__((address_space(1))) void*)g,
                                     (__attribute__((address_space(3))) void*)lds,
                                     16, 0, 0);
}

// ---------------- Q prepass: inv-norm + bf16 conversion, one wave per row --
__global__ __launch_bounds__(64) void qnorm_kernel(const float* __restrict__ q,
                                                   float* __restrict__ invq,
                                                   __bf16* __restrict__ qb) {
    const int row  = blockIdx.x;          // 0..1023 (= l*256+n)
    const int lane = threadIdx.x;         // 0..63, covers floats [lane*16, +16)
    const f32x4* p = (const f32x4*)(q + (size_t)row * K_D) + lane * 4;
    f32x4 v[4];
    float ss = 0.f;
#pragma unroll
    for (int i = 0; i < 4; ++i) {
        v[i] = p[i];
        ss += v[i][0]*v[i][0] + v[i][1]*v[i][1] + v[i][2]*v[i][2] + v[i][3]*v[i][3];
    }
    bf16x8* o = (bf16x8*)(qb + (size_t)row * K_D + lane * 16);
    o[0] = cvt8(v[0], v[1]);              // same rounding as before (cvt8)
    o[1] = cvt8(v[2], v[3]);
#pragma unroll
    for (int off = 32; off >= 1; off >>= 1) ss += __shfl_xor(ss, off, 64);
    if (lane == 0) invq[row] = 1.f / fmaxf(sqrtf(ss), 1e-8f);
}

// ---------------- main: LDS-staged B (dbuf), bf16 A from global -----------
__global__ __launch_bounds__(256, 3) void sim_kernel(const __bf16* __restrict__ Qb,
                                                     const float* __restrict__ G,
                                                     const float* __restrict__ invq,
                                                     float* __restrict__ cmax) {
    __shared__ __align__(16) float Bs[2][BM * 32];   // 2 x 8KB double buffer

    const int c    = blockIdx.x;          // m-chunk 0..799
    const int l    = blockIdx.y;          // layer 0..3
    const int wave = threadIdx.x >> 6;    // 0..3
    const int lane = threadIdx.x & 63;
    const int qd   = lane >> 4;           // quad 0..3
    const int cc   = lane & 15;

    const int m0 = c * BM;
    const int n0 = wave * 64;

    // ---- staging addresses. Wave w stages rows [w*8, w*8+8) (issue 0) and
    // +32 (issue 1) into linear LDS; the XOR swizzle is pre-applied to the
    // GLOBAL column offset so that the swizzled ds_read below sees (r,c).
    const int sr  = lane >> 3;                        // r & 7 for this lane
    const int scf = ((lane & 7) ^ sr) << 2;           // swizzled col (floats)
    const float* src0 = G + ((size_t)l * M_G + m0 + wave * 8 + sr) * K_D + scf;
    const float* src1 = src0 + (size_t)32 * K_D;      // +32 rows
    char* dst0 = (char*)Bs + wave * 1024;             // wave-uniform LDS base

    // ---- A frag rows: n = n0 + tn*16 + cc ; k = ks*32 + qd*8 + j (bf16)
    const __bf16* Ab = Qb + ((size_t)l * N_Q + n0 + cc) * K_D + qd * 8;

    // ---- swizzled LDS read offsets (bytes), constant across K-steps.
    // element (r, c): byte = r*128 + ((c*4) ^ ((r&7)<<4))
    int roff[4][2];
#pragma unroll
    for (int tm = 0; tm < 4; ++tm) {
        const int r = tm * 16 + cc;
        roff[tm][0] = r * 128 + ((qd * 32)      ^ ((r & 7) << 4));
        roff[tm][1] = r * 128 + ((qd * 32 + 16) ^ ((r & 7) << 4));
    }

    f32x4 acc[4][4];                       // [tn][tm] : C[n][m] bf16-dot
    float gss[4] = {0.f, 0.f, 0.f, 0.f};   // gallery row sumsq partials (fp32)
#pragma unroll
    for (int tn = 0; tn < 4; ++tn)
#pragma unroll
        for (int tm = 0; tm < 4; ++tm) acc[tn][tm] = (f32x4){0.f, 0.f, 0.f, 0.f};

    // ---- prologue: stage K-step 0, load A frags for step 0
    {
        gload16(src0, dst0);
        gload16(src1, dst0 + 4096);
    }
    bf16x8 afr[4];
#pragma unroll
    for (int tn = 0; tn < 4; ++tn)
        afr[tn] = *(const bf16x8*)(Ab + (size_t)(tn * 16) * K_D);
    __syncthreads();                      // vmcnt(0) drain: buf0 ready

    int cur = 0;
    for (int ks = 0; ks < KSTEPS; ++ks) {
        bf16x8 anx[4];
        if (ks + 1 < KSTEPS) {
            // stage next tile into the other buffer (in flight across compute)
            const size_t koF = (size_t)(ks + 1) * 32;
            char* d = (char*)Bs + (cur ^ 1) * 8192 + wave * 1024;
            gload16(src0 + koF, d);
            gload16(src1 + koF, d + 4096);
            // prefetch next A frags (L2-hot; completes by the barrier)
#pragma unroll
            for (int tn = 0; tn < 4; ++tn)
                anx[tn] = *(const bf16x8*)(Ab + (size_t)(tn * 16) * K_D + (ks + 1) * 32);
        }

        const char* bufc = (const char*)Bs + cur * 8192;
        bf16x8 bfr[4];
#pragma unroll
        for (int tm = 0; tm < 4; ++tm) {
            f32x4 a = *(const f32x4*)(bufc + roff[tm][0]);
            f32x4 b = *(const f32x4*)(bufc + roff[tm][1]);
            bfr[tm] = cvt8(a, b);
            gss[tm] += a[0]*a[0] + a[1]*a[1] + a[2]*a[2] + a[3]*a[3]
                     + b[0]*b[0] + b[1]*b[1] + b[2]*b[2] + b[3]*b[3];
        }
#pragma unroll
        for (int tn = 0; tn < 4; ++tn)
#pragma unroll
            for (int tm = 0; tm < 4; ++tm)
                acc[tn][tm] = __builtin_amdgcn_mfma_f32_16x16x32_bf16(afr[tn], bfr[tm],
                                                                      acc[tn][tm], 0, 0, 0);

        __syncthreads();                  // drains vmcnt: next buffer ready
        if (ks + 1 < KSTEPS) {
#pragma unroll
            for (int tn = 0; tn < 4; ++tn) afr[tn] = anx[tn];
        }
        cur ^= 1;
    }

    // ---- gallery inv-norms: complete each row's sumsq across the 4 quads.
    float invg[4];
#pragma unroll
    for (int tm = 0; tm < 4; ++tm) {
        float s = gss[tm];
        s += __shfl_xor(s, 16, 64);
        s += __shfl_xor(s, 32, 64);
        invg[tm] = 1.f / fmaxf(sqrtf(s), 1e-8f);
    }

    // ---- epilogue: scale by invg, max over the 64 gallery cols, then invq.
    // C/D layout: row = qd*4 + r (query), col = cc (gallery).
    float* cmrow = cmax + ((size_t)l * NCHUNK + c) * N_Q;
#pragma unroll
    for (int tn = 0; tn < 4; ++tn) {
        const f32x4 iv4 = *(const f32x4*)(invq + l * N_Q + n0 + tn * 16 + qd * 4);
        f32x4 v4;
#pragma unroll
        for (int r = 0; r < 4; ++r) {
            float v = acc[tn][0][r] * invg[0];
            v = fmaxf(v, acc[tn][1][r] * invg[1]);
            v = fmaxf(v, acc[tn][2][r] * invg[2]);
            v = fmaxf(v, acc[tn][3][r] * invg[3]);
#pragma unroll
            for (int off = 8; off >= 1; off >>= 1) v = fmaxf(v, __shfl_xor(v, off, 64));
            v4[r] = v * iv4[r];   // invq > 0: monotone, applied after max
        }
        if (cc == 0) *(f32x4*)(cmrow + n0 + tn * 16 + qd * 4) = v4;
    }
}

// ---------------- reduce 800 chunk-maxes -> 8 segment-maxes per (l,n) ------
__global__ __launch_bounds__(256) void redc_kernel(const float* __restrict__ cmax,
                                                   float* __restrict__ pmax) {
    const int s = blockIdx.x;   // 0..7
    const int l = blockIdx.y;   // 0..3
    const int n = threadIdx.x;  // 0..255
    const float* p = cmax + ((size_t)l * NCHUNK + s * (NCHUNK / 8)) * N_Q + n;
    float m = -3e38f;
    for (int c = 0; c < NCHUNK / 8; ++c) m = fmaxf(m, p[(size_t)c * N_Q]);
    pmax[(l * 8 + s) * N_Q + n] = m;
}

// ---------------- final: mean over layers, 1 - sim, fp32 out --------------
__global__ __launch_bounds__(256) void final_kernel(const float* __restrict__ pmax,
                                                    float* __restrict__ out) {
    const int n = threadIdx.x;
    float sum = 0.f;
#pragma unroll
    for (int l = 0; l < 4; ++l) {
        float m = -3e38f;
#pragma unroll
        for (int s = 0; s < 8; ++s) m = fmaxf(m, pmax[(l * 8 + s) * N_Q + n]);
        sum += m;
    }
    out[n] = 1.0f - 0.25f * sum;
}

extern "C" void kernel_launch(void* const* d_in, const int* in_sizes, int n_in,
                              void* d_out, int out_size, void* d_ws, size_t ws_size,
                              hipStream_t stream) {
    const float* Q = (const float*)d_in[0];   // [4,256,1024] fp32
    const float* G = (const float*)d_in[1];   // [4,51200,1024] fp32
    float* out = (float*)d_out;               // 256 fp32

    float* invq  = (float*)d_ws;                           // 1024 f
    float* cmax  = invq + 1024;                            // 4*800*256 f = 3.125 MB
    float* pmax  = cmax + (size_t)L_LAYERS * NCHUNK * N_Q; // 32*256 f
    __bf16* qb   = (__bf16*)(pmax + 32 * N_Q);             // 4*256*1024 bf16 = 2 MB (16B-aligned)
    // total ws use ~5.2 MB; every cell written before read (poison-safe)

    qnorm_kernel<<<dim3(L_LAYERS * N_Q), dim3(64), 0, stream>>>(Q, invq, qb);
    sim_kernel<<<dim3(NCHUNK, L_LAYERS), dim3(256), 0, stream>>>(qb, G, invq, cmax);
    redc_kernel<<<dim3(8, L_LAYERS), dim3(256), 0, stream>>>(cmax, pmax);
    final_kernel<<<dim3(1), dim3(256), 0, stream>>>(pmax, out);
}